// Round 1
// baseline (717.264 us; speedup 1.0000x reference)
//
#include <hip/hip_runtime.h>

// EncConvNet fused: conv7x7s3 + bias + sq -> fc1 + bias + sq -> fc2 + bias
// 32 images per 256-thread block. fp32 throughout (no fp32 MFMA on CDNA4;
// vector-ALU FMA with SGPR weight operands for conv, L1-broadcast vector
// loads for fc1 weights).

#define IMG_PER_BLOCK 32
#define H_STRIDE 260   // 256 + 4: 16B-aligned rows, banks 4*g mod 32 distinct for 8 imgs/wave

__global__ __launch_bounds__(256, 2)
void encconv_fused(const float* __restrict__ x,
                   const float* __restrict__ conv_w,
                   const float* __restrict__ conv_b,
                   const float* __restrict__ fc1_w,
                   const float* __restrict__ fc1_b,
                   const float* __restrict__ fc2_w,
                   const float* __restrict__ fc2_b,
                   float* __restrict__ out,
                   int B)
{
    __shared__ float h_lds[IMG_PER_BLOCK * H_STRIDE];

    const int tid = threadIdx.x;
    const int blk = blockIdx.x;

    // ---------------- Phase 1: conv 7x7 stride3 + bias + square -> LDS ----------------
    {
        const int g = tid >> 3;      // image within block, 0..31
        const int y = tid & 7;       // conv output row, 0..7
        const long img = (long)blk * IMG_PER_BLOCK + g;

        float acc[4][8];
        #pragma unroll
        for (int c = 0; c < 4; ++c)
            #pragma unroll
            for (int xx = 0; xx < 8; ++xx)
                acc[c][xx] = 0.f;

        if (img < B) {
            const float* xi = x + img * 784;
            #pragma unroll 1
            for (int rr = 0; rr < 7; ++rr) {   // rr uniform across block -> weight idx uniform -> s_load
                const float* rp = xi + (3 * y + rr) * 28;
                float4 rv[7];
                #pragma unroll
                for (int t = 0; t < 7; ++t)
                    rv[t] = *(const float4*)(rp + 4 * t);
                float row[28];
                #pragma unroll
                for (int t = 0; t < 7; ++t) {
                    row[4 * t + 0] = rv[t].x;
                    row[4 * t + 1] = rv[t].y;
                    row[4 * t + 2] = rv[t].z;
                    row[4 * t + 3] = rv[t].w;
                }
                #pragma unroll
                for (int c = 0; c < 4; ++c) {
                    #pragma unroll
                    for (int kx = 0; kx < 7; ++kx) {
                        const float w = conv_w[c * 49 + rr * 7 + kx];  // uniform -> SGPR operand
                        #pragma unroll
                        for (int xx = 0; xx < 8; ++xx)
                            acc[c][xx] = fmaf(row[3 * xx + kx], w, acc[c][xx]);
                    }
                }
            }
        }

        // bias + square -> h_lds[g][c*64 + y*8 + x]
        float* hg = h_lds + g * H_STRIDE;
        #pragma unroll
        for (int c = 0; c < 4; ++c) {
            const float b = conv_b[c];
            float4 v0, v1;
            v0.x = acc[c][0] + b; v0.y = acc[c][1] + b; v0.z = acc[c][2] + b; v0.w = acc[c][3] + b;
            v1.x = acc[c][4] + b; v1.y = acc[c][5] + b; v1.z = acc[c][6] + b; v1.w = acc[c][7] + b;
            v0.x *= v0.x; v0.y *= v0.y; v0.z *= v0.z; v0.w *= v0.w;
            v1.x *= v1.x; v1.y *= v1.y; v1.z *= v1.z; v1.w *= v1.w;
            *(float4*)(hg + c * 64 + y * 8 + 0) = v0;
            *(float4*)(hg + c * 64 + y * 8 + 4) = v1;
        }
    }

    __syncthreads();

    // ---------------- Phase 2: fc1 (256 -> 64) + bias + square ----------------
    // thread = (image g2, output-slice os): outputs o in [os*8, os*8+8)
    const int g2 = tid >> 3;     // 0..31
    const int os = tid & 7;      // 0..7
    const float* hg = h_lds + g2 * H_STRIDE;

    float acc2[8];
    #pragma unroll
    for (int o = 0; o < 8; ++o) acc2[o] = 0.f;

    const float* w1base = fc1_w + os * 8 * 256;

    #pragma unroll 1
    for (int ib = 0; ib < 16; ++ib) {
        // 16 h values from LDS (broadcast across os, distinct banks across g2)
        float4 h0 = *(const float4*)(hg + ib * 16 + 0);
        float4 h1 = *(const float4*)(hg + ib * 16 + 4);
        float4 h2 = *(const float4*)(hg + ib * 16 + 8);
        float4 h3 = *(const float4*)(hg + ib * 16 + 12);
        #pragma unroll
        for (int o = 0; o < 8; ++o) {
            const float* wr = w1base + o * 256 + ib * 16;
            float4 w0 = *(const float4*)(wr + 0);
            float4 w1 = *(const float4*)(wr + 4);
            float4 w2 = *(const float4*)(wr + 8);
            float4 w3 = *(const float4*)(wr + 12);
            float s = acc2[o];
            s = fmaf(h0.x, w0.x, s); s = fmaf(h0.y, w0.y, s);
            s = fmaf(h0.z, w0.z, s); s = fmaf(h0.w, w0.w, s);
            s = fmaf(h1.x, w1.x, s); s = fmaf(h1.y, w1.y, s);
            s = fmaf(h1.z, w1.z, s); s = fmaf(h1.w, w1.w, s);
            s = fmaf(h2.x, w2.x, s); s = fmaf(h2.y, w2.y, s);
            s = fmaf(h2.z, w2.z, s); s = fmaf(h2.w, w2.w, s);
            s = fmaf(h3.x, w3.x, s); s = fmaf(h3.y, w3.y, s);
            s = fmaf(h3.z, w3.z, s); s = fmaf(h3.w, w3.w, s);
            acc2[o] = s;
        }
    }

    // bias + square
    float h2v[8];
    {
        float4 b0 = *(const float4*)(fc1_b + os * 8 + 0);
        float4 b1 = *(const float4*)(fc1_b + os * 8 + 4);
        float bb[8] = {b0.x, b0.y, b0.z, b0.w, b1.x, b1.y, b1.z, b1.w};
        #pragma unroll
        for (int o = 0; o < 8; ++o) {
            float v = acc2[o] + bb[o];
            h2v[o] = v * v;
        }
    }

    // ---------------- Phase 3: fc2 (64 -> 10), partial + 8-lane reduction ----------------
    float p[10];
    #pragma unroll
    for (int j = 0; j < 10; ++j) {
        const float* w2 = fc2_w + j * 64 + os * 8;
        float4 a0 = *(const float4*)(w2 + 0);
        float4 a1 = *(const float4*)(w2 + 4);
        float s = 0.f;
        s = fmaf(h2v[0], a0.x, s); s = fmaf(h2v[1], a0.y, s);
        s = fmaf(h2v[2], a0.z, s); s = fmaf(h2v[3], a0.w, s);
        s = fmaf(h2v[4], a1.x, s); s = fmaf(h2v[5], a1.y, s);
        s = fmaf(h2v[6], a1.z, s); s = fmaf(h2v[7], a1.w, s);
        p[j] = s;
    }

    // reduce across the 8 os-lanes (lanes g2*8 .. g2*8+7)
    #pragma unroll
    for (int j = 0; j < 10; ++j) {
        p[j] += __shfl_xor(p[j], 1, 64);
        p[j] += __shfl_xor(p[j], 2, 64);
        p[j] += __shfl_xor(p[j], 4, 64);
        p[j] += fc2_b[j];
    }

    const long img2 = (long)blk * IMG_PER_BLOCK + g2;
    if (img2 < B) {
        float* op = out + img2 * 10;
        // lane os writes j = os (and lanes 0,1 also write 8,9)
        op[os] = p[os];
        if (os < 2) op[os + 8] = p[os + 8];
    }
}

extern "C" void kernel_launch(void* const* d_in, const int* in_sizes, int n_in,
                              void* d_out, int out_size, void* d_ws, size_t ws_size,
                              hipStream_t stream) {
    const float* x      = (const float*)d_in[0];
    const float* conv_w = (const float*)d_in[1];
    const float* conv_b = (const float*)d_in[2];
    const float* fc1_w  = (const float*)d_in[3];
    const float* fc1_b  = (const float*)d_in[4];
    const float* fc2_w  = (const float*)d_in[5];
    const float* fc2_b  = (const float*)d_in[6];
    float* out = (float*)d_out;

    const int B = in_sizes[0] / 784;
    const int blocks = (B + IMG_PER_BLOCK - 1) / IMG_PER_BLOCK;

    encconv_fused<<<blocks, 256, 0, stream>>>(x, conv_w, conv_b, fc1_w, fc1_b,
                                              fc2_w, fc2_b, out, B);
}

// Round 2
// 358.428 us; speedup vs baseline: 2.0011x; 2.0011x over previous
//
#include <hip/hip_runtime.h>

// EncConvNet fused v2: conv7x7s3+sq -> fc1+sq -> fc2, one kernel.
// 512 threads / 64 images per block, 1 block/CU (LDS 138.8 KB).
// Key structure:
//  - x staged to LDS in 8-image chunks, double-buffered, via coalesced
//    register prefetch (loads issued after the barrier so conv compute of
//    the current chunk hides the HBM latency of the next).
//  - fc1 weights are wave-uniform (wave w -> outputs 8w..8w+7, lanes = 64
//    images) -> s_load_dwordx4, SGPR operand in v_fma_f32. Kills the 4.2 GB
//    of per-thread weight re-reads that made R1 L1-request-bound.
//  - h / h2 stored k-major (slot = k4*64 + img) so the hot ds_read_b128 in
//    fc1/fc2 is lane-contiguous (optimal LDS pattern).

#define BLK_IMGS    64
#define CHUNK_IMGS  8
#define NCHUNK      8
#define XCH_FLOATS  (CHUNK_IMGS * 784)   // 6272 floats per chunk

// LDS float offsets
#define LDS_XBUF    0                    // 2 * 6272 = 12544
#define LDS_H       12544                // 64 k4-chunks * 64 imgs * 4 = 16384
#define LDS_H2      28928                // 16 * 64 * 4 = 4096
#define LDS_W2      33024                // 16 * 16 * 4 = 1024
#define LDS_OUT     34048                // 640
#define LDS_TOTAL_F 34688                // floats -> 138752 bytes

__global__ __launch_bounds__(512, 2)
void encconv_fused2(const float* __restrict__ x,
                    const float* __restrict__ conv_w,
                    const float* __restrict__ conv_b,
                    const float* __restrict__ fc1_w,
                    const float* __restrict__ fc1_b,
                    const float* __restrict__ fc2_w,
                    const float* __restrict__ fc2_b,
                    float* __restrict__ out)
{
    extern __shared__ float lds[];
    float*  xbuf = lds + LDS_XBUF;
    float4* hb   = (float4*)(lds + LDS_H);
    float4* h2b  = (float4*)(lds + LDS_H2);
    float4* w2b  = (float4*)(lds + LDS_W2);
    float*  ob   = lds + LDS_OUT;

    const int tid = threadIdx.x;
    const int blk = blockIdx.x;
    const long base_img = (long)blk * BLK_IMGS;

    // ---- conv-phase thread roles: tid = g*64 + y*8 + c*2 + xh ----
    const int g  = tid >> 6;         // wave id == image-in-chunk, 0..7
    const int y  = (tid >> 3) & 7;   // conv output row
    const int c  = (tid >> 1) & 3;   // channel
    const int xh = tid & 1;          // x-half (outputs 4*xh .. 4*xh+3)

    // per-lane conv taps for channel c (one-time, L1-broadcast across lanes)
    float wv[49];
    #pragma unroll
    for (int i = 0; i < 49; ++i) wv[i] = conv_w[c * 49 + i];
    const float cb = conv_b[c];

    // stage fc2_w into LDS, k-major: slot = kk*16 + j
    if (tid < 160) {
        float4 v = *(const float4*)(fc2_w + tid * 4);
        int e  = tid * 4;
        int j  = e >> 6;          // 0..9
        int kk = (e & 63) >> 2;   // 0..15
        w2b[kk * 16 + j] = v;
    }

    const float* xblk = x + base_img * 784;

    // ---- prefetch chunk 0 into registers (coalesced) ----
    float4 pf0, pf1, pf2, pf3;
    {
        const float* src = xblk;
        pf0 = *(const float4*)(src + 4 * tid);
        pf1 = *(const float4*)(src + 4 * (tid + 512));
        pf2 = *(const float4*)(src + 4 * (tid + 1024));
        if (tid < 32) pf3 = *(const float4*)(src + 4 * (tid + 1536));
    }

    // ---- conv over 8 chunks of 8 images, double-buffered LDS ----
    for (int ch = 0; ch < NCHUNK; ++ch) {
        float* xb = xbuf + (ch & 1) * XCH_FLOATS;

        // commit prefetched regs to LDS (lane-contiguous ds_write_b128)
        *(float4*)(xb + 4 * tid)          = pf0;
        *(float4*)(xb + 4 * (tid + 512))  = pf1;
        *(float4*)(xb + 4 * (tid + 1024)) = pf2;
        if (tid < 32) *(float4*)(xb + 4 * (tid + 1536)) = pf3;
        __syncthreads();

        // issue next chunk's prefetch; conv compute below hides its latency
        if (ch + 1 < NCHUNK) {
            const float* src = xblk + (ch + 1) * XCH_FLOATS;
            pf0 = *(const float4*)(src + 4 * tid);
            pf1 = *(const float4*)(src + 4 * (tid + 512));
            pf2 = *(const float4*)(src + 4 * (tid + 1024));
            if (tid < 32) pf3 = *(const float4*)(src + 4 * (tid + 1536));
        }

        // conv: image g of this chunk, row y, channel c, outputs 4xh..4xh+3
        float acc0 = 0.f, acc1 = 0.f, acc2 = 0.f, acc3 = 0.f;
        const float* xi = xb + g * 784;
        #pragma unroll
        for (int rr = 0; rr < 7; ++rr) {
            const float* rp = xi + (3 * y + rr) * 28 + 12 * xh;  // 16B aligned
            float4 r0 = *(const float4*)(rp + 0);
            float4 r1 = *(const float4*)(rp + 4);
            float4 r2 = *(const float4*)(rp + 8);
            float4 r3 = *(const float4*)(rp + 12);
            float r[16] = { r0.x, r0.y, r0.z, r0.w,
                            r1.x, r1.y, r1.z, r1.w,
                            r2.x, r2.y, r2.z, r2.w,
                            r3.x, r3.y, r3.z, r3.w };
            #pragma unroll
            for (int kx = 0; kx < 7; ++kx) {
                const float w = wv[rr * 7 + kx];
                acc0 = fmaf(r[0 + kx], w, acc0);
                acc1 = fmaf(r[3 + kx], w, acc1);
                acc2 = fmaf(r[6 + kx], w, acc2);
                acc3 = fmaf(r[9 + kx], w, acc3);
            }
        }

        // bias + square -> h (k-major: chunk index k4 = c*16 + y*2 + xh)
        float4 hv;
        hv.x = acc0 + cb; hv.x *= hv.x;
        hv.y = acc1 + cb; hv.y *= hv.y;
        hv.z = acc2 + cb; hv.z *= hv.z;
        hv.w = acc3 + cb; hv.w *= hv.w;
        hb[(c * 16 + y * 2 + xh) * 64 + (ch * CHUNK_IMGS + g)] = hv;
        // no barrier needed here: next iter writes the OTHER x buffer; the
        // next iter's barrier orders h/x for all consumers.
    }
    __syncthreads();

    // ---- fc1: wave w8 -> outputs 8*w8..8*w8+7, lanes = 64 images ----
    {
        const int img = tid & 63;
        const int w8  = __builtin_amdgcn_readfirstlane(tid >> 6);  // uniform
        const float* wbase = fc1_w + (w8 * 8) * 256;

        float a0=0.f,a1=0.f,a2=0.f,a3=0.f,a4=0.f,a5=0.f,a6=0.f,a7=0.f;

        #pragma unroll 2
        for (int k4 = 0; k4 < 64; ++k4) {
            float4 h4 = hb[k4 * 64 + img];            // lane-contiguous b128
            const float* wp = wbase + k4 * 4;
            float4 w0 = *(const float4*)(wp + 0 * 256);   // uniform -> s_load
            float4 w1 = *(const float4*)(wp + 1 * 256);
            float4 w2 = *(const float4*)(wp + 2 * 256);
            float4 w3 = *(const float4*)(wp + 3 * 256);
            float4 w4 = *(const float4*)(wp + 4 * 256);
            float4 w5 = *(const float4*)(wp + 5 * 256);
            float4 w6 = *(const float4*)(wp + 6 * 256);
            float4 w7 = *(const float4*)(wp + 7 * 256);
            a0 = fmaf(h4.x,w0.x,a0); a0 = fmaf(h4.y,w0.y,a0); a0 = fmaf(h4.z,w0.z,a0); a0 = fmaf(h4.w,w0.w,a0);
            a1 = fmaf(h4.x,w1.x,a1); a1 = fmaf(h4.y,w1.y,a1); a1 = fmaf(h4.z,w1.z,a1); a1 = fmaf(h4.w,w1.w,a1);
            a2 = fmaf(h4.x,w2.x,a2); a2 = fmaf(h4.y,w2.y,a2); a2 = fmaf(h4.z,w2.z,a2); a2 = fmaf(h4.w,w2.w,a2);
            a3 = fmaf(h4.x,w3.x,a3); a3 = fmaf(h4.y,w3.y,a3); a3 = fmaf(h4.z,w3.z,a3); a3 = fmaf(h4.w,w3.w,a3);
            a4 = fmaf(h4.x,w4.x,a4); a4 = fmaf(h4.y,w4.y,a4); a4 = fmaf(h4.z,w4.z,a4); a4 = fmaf(h4.w,w4.w,a4);
            a5 = fmaf(h4.x,w5.x,a5); a5 = fmaf(h4.y,w5.y,a5); a5 = fmaf(h4.z,w5.z,a5); a5 = fmaf(h4.w,w5.w,a5);
            a6 = fmaf(h4.x,w6.x,a6); a6 = fmaf(h4.y,w6.y,a6); a6 = fmaf(h4.z,w6.z,a6); a6 = fmaf(h4.w,w6.w,a6);
            a7 = fmaf(h4.x,w7.x,a7); a7 = fmaf(h4.y,w7.y,a7); a7 = fmaf(h4.z,w7.z,a7); a7 = fmaf(h4.w,w7.w,a7);
        }

        // bias + square -> h2 (k-major), two lane-contiguous b128 writes
        const float* bp = fc1_b + w8 * 8;   // uniform -> s_load
        float4 p0, p1;
        p0.x = a0 + bp[0]; p0.x *= p0.x;
        p0.y = a1 + bp[1]; p0.y *= p0.y;
        p0.z = a2 + bp[2]; p0.z *= p0.z;
        p0.w = a3 + bp[3]; p0.w *= p0.w;
        p1.x = a4 + bp[4]; p1.x *= p1.x;
        p1.y = a5 + bp[5]; p1.y *= p1.y;
        p1.z = a6 + bp[6]; p1.z *= p1.z;
        p1.w = a7 + bp[7]; p1.w *= p1.w;
        h2b[(w8 * 2 + 0) * 64 + img] = p0;
        h2b[(w8 * 2 + 1) * 64 + img] = p1;
    }
    __syncthreads();

    // ---- fc2: thread (im3 = tid>>3, q = tid&7); j = q, and j = 8+q for q<2 ----
    {
        const int im3 = tid >> 3;
        const int q   = tid & 7;

        float s1 = 0.f;
        #pragma unroll
        for (int k4 = 0; k4 < 16; ++k4) {
            float4 hh = h2b[k4 * 64 + im3];
            float4 wA = w2b[k4 * 16 + q];
            s1 = fmaf(hh.x, wA.x, s1); s1 = fmaf(hh.y, wA.y, s1);
            s1 = fmaf(hh.z, wA.z, s1); s1 = fmaf(hh.w, wA.w, s1);
        }
        ob[im3 * 10 + q] = s1 + fc2_b[q];

        if (q < 2) {
            float s2 = 0.f;
            #pragma unroll
            for (int k4 = 0; k4 < 16; ++k4) {
                float4 hh = h2b[k4 * 64 + im3];
                float4 wB = w2b[k4 * 16 + 8 + q];
                s2 = fmaf(hh.x, wB.x, s2); s2 = fmaf(hh.y, wB.y, s2);
                s2 = fmaf(hh.z, wB.z, s2); s2 = fmaf(hh.w, wB.w, s2);
            }
            ob[im3 * 10 + 8 + q] = s2 + fc2_b[8 + q];
        }
    }
    __syncthreads();

    // ---- coalesced output store: 640 floats per block ----
    if (tid < 160) {
        float4 v = *(const float4*)(ob + tid * 4);
        *(float4*)(out + (long)blk * 640 + tid * 4) = v;
    }
}

extern "C" void kernel_launch(void* const* d_in, const int* in_sizes, int n_in,
                              void* d_out, int out_size, void* d_ws, size_t ws_size,
                              hipStream_t stream) {
    const float* x      = (const float*)d_in[0];
    const float* conv_w = (const float*)d_in[1];
    const float* conv_b = (const float*)d_in[2];
    const float* fc1_w  = (const float*)d_in[3];
    const float* fc1_b  = (const float*)d_in[4];
    const float* fc2_w  = (const float*)d_in[5];
    const float* fc2_b  = (const float*)d_in[6];
    float* out = (float*)d_out;

    const int B = in_sizes[0] / 784;
    const int blocks = (B + BLK_IMGS - 1) / BLK_IMGS;   // 1024 for B=65536
    const size_t lds_bytes = LDS_TOTAL_F * sizeof(float);  // 138752

    // gfx950 allows 160 KiB LDS/workgroup; raise the dynamic-LDS cap (idempotent).
    static bool attr_set = false;
    if (!attr_set) {
        (void)hipFuncSetAttribute((const void*)encconv_fused2,
                                  hipFuncAttributeMaxDynamicSharedMemorySize,
                                  (int)lds_bytes);
        attr_set = true;
    }

    encconv_fused2<<<blocks, 512, lds_bytes, stream>>>(
        x, conv_w, conv_b, fc1_w, fc1_b, fc2_w, fc2_b, out);
}